// Round 1
// baseline (1412.178 us; speedup 1.0000x reference)
//
#include <hip/hip_runtime.h>
#include <cstddef>

#define NPASS 12
#define NCF   10

struct TFKeys { unsigned k[2 * NCF]; };

// Threefry-2x32, 20 rounds (JAX-compatible).
__host__ __device__ __forceinline__ void tf2x32(unsigned k0, unsigned k1,
                                                unsigned x0, unsigned x1,
                                                unsigned& o0, unsigned& o1) {
  const unsigned ks2 = k0 ^ k1 ^ 0x1BD11BDAu;
  x0 += k0; x1 += k1;
#define TF_R(r) x0 += x1; x1 = (x1 << (r)) | (x1 >> (32 - (r))); x1 ^= x0;
  TF_R(13) TF_R(15) TF_R(26) TF_R(6)
  x0 += k1;  x1 += ks2 + 1u;
  TF_R(17) TF_R(29) TF_R(16) TF_R(24)
  x0 += ks2; x1 += k0 + 2u;
  TF_R(13) TF_R(15) TF_R(26) TF_R(6)
  x0 += k0;  x1 += k1 + 3u;
  TF_R(17) TF_R(29) TF_R(16) TF_R(24)
  x0 += k1;  x1 += ks2 + 4u;
  TF_R(13) TF_R(15) TF_R(26) TF_R(6)
  x0 += ks2; x1 += k0 + 5u;
#undef TF_R
  o0 = x0; o1 = x1;
}

__device__ __forceinline__ float u01(unsigned bits) {
  // jax _uniform: bitcast((bits>>9)|0x3f800000) - 1.0  in [0,1)
  return __uint_as_float((bits >> 9) | 0x3f800000u) - 1.0f;
}

// B=32,T=512,N=8 -> S=131072 samples; D=256, A=64, H1=128, H2=64, DIN=320.
// 4096 workgroups x 256 threads; each WG owns 32 samples:
//   local m in [0,16)  -> global wg*16+m
//   local m in [16,32) -> global 65536 + wg*16 + (m-16)
__global__ __launch_bounds__(256, 2)
void infl_kernel(const float* __restrict__ obs, const float* __restrict__ actions,
                 const float* __restrict__ W1, const float* __restrict__ b1,
                 const float* __restrict__ W2, const float* __restrict__ b2,
                 const float* __restrict__ W3, const float* __restrict__ b3,
                 float* __restrict__ out, TFKeys keys) {
  // LDS: 8192 + 4224 + 2080 + 256 floats = 59,008 B  (< 64 KB -> 2 WG/CU)
  __shared__ __align__(16) float s_wreg[8192];     // staged W1a / W2 / W3 / W1-obs blocks
  __shared__ __align__(16) float s_h1[32 * 132];   // h1 (passes) | obs half (phase 1)
  __shared__ __align__(16) float s_act[32 * 65];   // act (L1 input) | h2 (L3 input)
  __shared__ float s_b1[128];
  __shared__ float s_b2[64];
  __shared__ float s_b3[64];

  const int t  = threadIdx.x;
  const int wg = blockIdx.x;

  // biases (once)
  if (t < 128)      s_b1[t] = b1[t];
  else if (t < 192) s_b2[t - 128] = b2[t - 128];
  else              s_b3[t - 192] = b3[t - 192];

  // thread maps
  const int ms  = t >> 5;   // 0..7  -> samples 4*ms..4*ms+3   (phase1 / L1)
  const int ns  = t & 31;   // 0..31 -> h1 neurons 4*ns..4*ns+3
  const int ms2 = t >> 4;   // 0..15 -> samples 2*ms2, 2*ms2+1 (L2 / L3 / epilogue)
  const int ns2 = t & 15;   //       -> cols 4*ns2..4*ns2+3
  const int sr  = t >> 3;   // 0..31  staging row
  const int sc  = t & 7;    // 0..7   staging chunk

  auto gsample = [&](int m) -> int {
    return (m < 16) ? (wg * 16 + m) : (65536 + wg * 16 + (m - 16));
  };
  const int g_sr = gsample(sr);

  float hobs[4][4];
#pragma unroll
  for (int r = 0; r < 4; ++r)
#pragma unroll
    for (int c = 0; c < 4; ++c) hobs[r][c] = 0.f;

  // ---------------- phase 1: h1_obs = obs @ W1[0:256,:]  (accumulated in regs)
  for (int h = 0; h < 2; ++h) {
    __syncthreads();  // s_h1 free (prev compute done)
    {
      // stage obs half [32 rows x 128 cols] into s_h1 (stride 132)
      const float* src = obs + (size_t)g_sr * 256 + h * 128 + sc * 16;
      float* dst = &s_h1[sr * 132 + sc * 16];
#pragma unroll
      for (int i = 0; i < 4; ++i)
        *(float4*)(dst + 4 * i) = *(const float4*)(src + 4 * i);
    }
    for (int bb = 0; bb < 2; ++bb) {
      __syncthreads();  // s_wreg free; obs staged
      {
        // stage 64 rows of W1 (rows h*128+bb*64 .. +64) -> s_wreg[64][128]
        const float4* src = (const float4*)(W1 + (size_t)(h * 128 + bb * 64) * 128);
#pragma unroll
        for (int i = 0; i < 8; ++i)
          ((float4*)s_wreg)[t + (i << 8)] = src[t + (i << 8)];
      }
      __syncthreads();
      const int cb = bb * 64;
#pragma unroll 4
      for (int kk = 0; kk < 64; ++kk) {
        const float4 wv = *(const float4*)&s_wreg[kk * 128 + (ns << 2)];
#pragma unroll
        for (int r = 0; r < 4; ++r) {
          const float a = s_h1[(4 * ms + r) * 132 + cb + kk];
          hobs[r][0] = fmaf(a, wv.x, hobs[r][0]);
          hobs[r][1] = fmaf(a, wv.y, hobs[r][1]);
          hobs[r][2] = fmaf(a, wv.z, hobs[r][2]);
          hobs[r][3] = fmaf(a, wv.w, hobs[r][3]);
        }
      }
    }
  }
  // fold b1 into the persistent obs pre-activation
#pragma unroll
  for (int c = 0; c < 4; ++c) {
    const float bv = s_b1[(ns << 2) + c];
#pragma unroll
    for (int r = 0; r < 4; ++r) hobs[r][c] += bv;
  }

  float pwith[2][4];
  float pacc[2][4];
#pragma unroll
  for (int r = 0; r < 2; ++r)
#pragma unroll
    for (int c = 0; c < 4; ++c) pacc[r][c] = 0.f;

  // ---------------- 12 passes: 0=real actions, 1=zeros, 2..11=counterfactuals
  for (int pass = 0; pass < NPASS; ++pass) {
    __syncthreads();  // s_act (h2) and s_wreg free
    if (pass == 0) {
      const float* src = actions + (size_t)g_sr * 64 + sc * 8;
      const float4 v0 = *(const float4*)(src);
      const float4 v1 = *(const float4*)(src + 4);
      float* dst = &s_act[sr * 65 + sc * 8];
      dst[0] = v0.x; dst[1] = v0.y; dst[2] = v0.z; dst[3] = v0.w;
      dst[4] = v1.x; dst[5] = v1.y; dst[6] = v1.z; dst[7] = v1.w;
    } else if (pass == 1) {
      for (int i = t; i < 32 * 65; i += 256) s_act[i] = 0.f;
    } else {
      // partitionable threefry: bits(i) = w0^w1 of tf(subkey, (0, i)); i = s*64+a
      const unsigned k0 = keys.k[2 * (pass - 2)];
      const unsigned k1 = keys.k[2 * (pass - 2) + 1];
      const unsigned base = (unsigned)g_sr * 64u + (unsigned)(sc * 8);
      float* dst = &s_act[sr * 65 + sc * 8];
#pragma unroll
      for (int e = 0; e < 8; ++e) {
        unsigned o0, o1;
        tf2x32(k0, k1, 0u, base + (unsigned)e, o0, o1);
        dst[e] = u01(o0 ^ o1);
      }
    }
    {  // stage W1 action-part (rows 256..319)
      const float4* src = (const float4*)(W1 + 256 * 128);
#pragma unroll
      for (int i = 0; i < 8; ++i)
        ((float4*)s_wreg)[t + (i << 8)] = src[t + (i << 8)];
    }
    __syncthreads();

    // ---- layer 1: h1 = relu(h1_obs + act @ W1a)
    float acc[4][4];
#pragma unroll
    for (int r = 0; r < 4; ++r)
#pragma unroll
      for (int c = 0; c < 4; ++c) acc[r][c] = 0.f;
#pragma unroll 4
    for (int k = 0; k < 64; ++k) {
      const float4 wv = *(const float4*)&s_wreg[k * 128 + (ns << 2)];
#pragma unroll
      for (int r = 0; r < 4; ++r) {
        const float a = s_act[(4 * ms + r) * 65 + k];
        acc[r][0] = fmaf(a, wv.x, acc[r][0]);
        acc[r][1] = fmaf(a, wv.y, acc[r][1]);
        acc[r][2] = fmaf(a, wv.z, acc[r][2]);
        acc[r][3] = fmaf(a, wv.w, acc[r][3]);
      }
    }
#pragma unroll
    for (int r = 0; r < 4; ++r) {
      float4 hv;
      hv.x = fmaxf(hobs[r][0] + acc[r][0], 0.f);
      hv.y = fmaxf(hobs[r][1] + acc[r][1], 0.f);
      hv.z = fmaxf(hobs[r][2] + acc[r][2], 0.f);
      hv.w = fmaxf(hobs[r][3] + acc[r][3], 0.f);
      *(float4*)&s_h1[(4 * ms + r) * 132 + (ns << 2)] = hv;
    }
    __syncthreads();

    {  // stage W2
      const float4* src = (const float4*)W2;
#pragma unroll
      for (int i = 0; i < 8; ++i)
        ((float4*)s_wreg)[t + (i << 8)] = src[t + (i << 8)];
    }
    __syncthreads();

    // ---- layer 2: h2 = relu(h1 @ W2 + b2)  (h2 overlays s_act)
    float acc2[2][4];
#pragma unroll
    for (int r = 0; r < 2; ++r)
#pragma unroll
      for (int c = 0; c < 4; ++c) acc2[r][c] = 0.f;
#pragma unroll 4
    for (int k = 0; k < 128; ++k) {
      const float4 wv = *(const float4*)&s_wreg[k * 64 + (ns2 << 2)];
      const float a0 = s_h1[(2 * ms2 + 0) * 132 + k];
      const float a1 = s_h1[(2 * ms2 + 1) * 132 + k];
      acc2[0][0] = fmaf(a0, wv.x, acc2[0][0]);
      acc2[0][1] = fmaf(a0, wv.y, acc2[0][1]);
      acc2[0][2] = fmaf(a0, wv.z, acc2[0][2]);
      acc2[0][3] = fmaf(a0, wv.w, acc2[0][3]);
      acc2[1][0] = fmaf(a1, wv.x, acc2[1][0]);
      acc2[1][1] = fmaf(a1, wv.y, acc2[1][1]);
      acc2[1][2] = fmaf(a1, wv.z, acc2[1][2]);
      acc2[1][3] = fmaf(a1, wv.w, acc2[1][3]);
    }
#pragma unroll
    for (int r = 0; r < 2; ++r)
#pragma unroll
      for (int c = 0; c < 4; ++c)
        s_act[(2 * ms2 + r) * 65 + (ns2 << 2) + c] =
            fmaxf(acc2[r][c] + s_b2[(ns2 << 2) + c], 0.f);
    __syncthreads();

    {  // stage W3
      const float4* src = (const float4*)W3;
#pragma unroll
      for (int i = 0; i < 4; ++i)
        ((float4*)s_wreg)[t + (i << 8)] = src[t + (i << 8)];
    }
    __syncthreads();

    // ---- layer 3: p = h2 @ W3 + b3 -> accumulate in regs
    float acc3[2][4];
#pragma unroll
    for (int r = 0; r < 2; ++r)
#pragma unroll
      for (int c = 0; c < 4; ++c) acc3[r][c] = 0.f;
#pragma unroll 4
    for (int k = 0; k < 64; ++k) {
      const float4 wv = *(const float4*)&s_wreg[k * 64 + (ns2 << 2)];
      const float a0 = s_act[(2 * ms2 + 0) * 65 + k];
      const float a1 = s_act[(2 * ms2 + 1) * 65 + k];
      acc3[0][0] = fmaf(a0, wv.x, acc3[0][0]);
      acc3[0][1] = fmaf(a0, wv.y, acc3[0][1]);
      acc3[0][2] = fmaf(a0, wv.z, acc3[0][2]);
      acc3[0][3] = fmaf(a0, wv.w, acc3[0][3]);
      acc3[1][0] = fmaf(a1, wv.x, acc3[1][0]);
      acc3[1][1] = fmaf(a1, wv.y, acc3[1][1]);
      acc3[1][2] = fmaf(a1, wv.z, acc3[1][2]);
      acc3[1][3] = fmaf(a1, wv.w, acc3[1][3]);
    }
    if (pass == 0) {
#pragma unroll
      for (int r = 0; r < 2; ++r)
#pragma unroll
        for (int c = 0; c < 4; ++c)
          pwith[r][c] = acc3[r][c] + s_b3[(ns2 << 2) + c];
    } else {
#pragma unroll
      for (int r = 0; r < 2; ++r)
#pragma unroll
        for (int c = 0; c < 4; ++c)
          pacc[r][c] += acc3[r][c] + s_b3[(ns2 << 2) + c];
    }
  }

  // ---------------- epilogue: mean_a q*(logq - logp), 16-lane shfl reductions
  const float inv11 = 1.0f / 11.0f;
#pragma unroll
  for (int r = 0; r < 2; ++r) {
    float pw[4], pa[4];
#pragma unroll
    for (int c = 0; c < 4; ++c) { pw[c] = pwith[r][c]; pa[c] = pacc[r][c] * inv11; }
    float mw = fmaxf(fmaxf(pw[0], pw[1]), fmaxf(pw[2], pw[3]));
    float ma = fmaxf(fmaxf(pa[0], pa[1]), fmaxf(pa[2], pa[3]));
#pragma unroll
    for (int off = 1; off < 16; off <<= 1) {
      mw = fmaxf(mw, __shfl_xor(mw, off, 64));
      ma = fmaxf(ma, __shfl_xor(ma, off, 64));
    }
    float sw = 0.f, sa = 0.f;
#pragma unroll
    for (int c = 0; c < 4; ++c) { sw += expf(pw[c] - mw); sa += expf(pa[c] - ma); }
#pragma unroll
    for (int off = 1; off < 16; off <<= 1) {
      sw += __shfl_xor(sw, off, 64);
      sa += __shfl_xor(sa, off, 64);
    }
    const float lzw = logf(sw), lza = logf(sa);
    float contrib = 0.f;
#pragma unroll
    for (int c = 0; c < 4; ++c) {
      const float lq = pa[c] - ma - lza;
      const float lp = pw[c] - mw - lzw;
      contrib += expf(lq) * (lq - lp);
    }
#pragma unroll
    for (int off = 1; off < 16; off <<= 1)
      contrib += __shfl_xor(contrib, off, 64);
    if (ns2 == 0) out[gsample(2 * ms2 + r)] = contrib * (1.0f / 64.0f);
  }
}

extern "C" void kernel_launch(void* const* d_in, const int* in_sizes, int n_in,
                              void* d_out, int out_size, void* d_ws, size_t ws_size,
                              hipStream_t stream) {
  (void)in_sizes; (void)n_in; (void)d_ws; (void)ws_size; (void)out_size;
  const float* obs     = (const float*)d_in[0];
  const float* actions = (const float*)d_in[1];
  const float* W1      = (const float*)d_in[2];
  const float* b1      = (const float*)d_in[3];
  const float* W2      = (const float*)d_in[4];
  const float* b2      = (const float*)d_in[5];
  const float* W3      = (const float*)d_in[6];
  const float* b3      = (const float*)d_in[7];

  // jax.random.split(jax.random.key(42), 10) with jax_threefry_partitionable=True:
  // subkey[j] = threefry2x32((0,42), (0, j))
  TFKeys keys;
  for (unsigned j = 0; j < NCF; ++j) {
    unsigned o0, o1;
    tf2x32(0u, 42u, 0u, j, o0, o1);
    keys.k[2 * j]     = o0;
    keys.k[2 * j + 1] = o1;
  }

  hipLaunchKernelGGL(infl_kernel, dim3(4096), dim3(256), 0, stream,
                     obs, actions, W1, b1, W2, b2, W3, b3, (float*)d_out, keys);
}

// Round 2
// 1333.809 us; speedup vs baseline: 1.0588x; 1.0588x over previous
//
#include <hip/hip_runtime.h>
#include <cstddef>

#define NCF 10

struct TFKeys { unsigned k[2 * NCF]; };

// Threefry-2x32, 20 rounds (JAX-compatible, partitionable semantics verified R1).
__host__ __device__ __forceinline__ void tf2x32(unsigned k0, unsigned k1,
                                                unsigned x0, unsigned x1,
                                                unsigned& o0, unsigned& o1) {
  const unsigned ks2 = k0 ^ k1 ^ 0x1BD11BDAu;
  x0 += k0; x1 += k1;
#define TF_R(r) x0 += x1; x1 = (x1 << (r)) | (x1 >> (32 - (r))); x1 ^= x0;
  TF_R(13) TF_R(15) TF_R(26) TF_R(6)
  x0 += k1;  x1 += ks2 + 1u;
  TF_R(17) TF_R(29) TF_R(16) TF_R(24)
  x0 += ks2; x1 += k0 + 2u;
  TF_R(13) TF_R(15) TF_R(26) TF_R(6)
  x0 += k0;  x1 += k1 + 3u;
  TF_R(17) TF_R(29) TF_R(16) TF_R(24)
  x0 += k1;  x1 += ks2 + 4u;
  TF_R(13) TF_R(15) TF_R(26) TF_R(6)
  x0 += ks2; x1 += k0 + 5u;
#undef TF_R
  o0 = x0; o1 = x1;
}

__device__ __forceinline__ float u01(unsigned bits) {
  return __uint_as_float((bits >> 9) | 0x3f800000u) - 1.0f;
}

// 16 FMAs: acc[0..3] (4 cols) += a.{x,y,z,w} (4 k) * w{0..3}.{col}
#define FMA4(ac, av, w0, w1, w2, w3)                                        \
  ac[0] = fmaf(av.x, w0.x, ac[0]); ac[0] = fmaf(av.y, w1.x, ac[0]);         \
  ac[0] = fmaf(av.z, w2.x, ac[0]); ac[0] = fmaf(av.w, w3.x, ac[0]);         \
  ac[1] = fmaf(av.x, w0.y, ac[1]); ac[1] = fmaf(av.y, w1.y, ac[1]);         \
  ac[1] = fmaf(av.z, w2.y, ac[1]); ac[1] = fmaf(av.w, w3.y, ac[1]);         \
  ac[2] = fmaf(av.x, w0.z, ac[2]); ac[2] = fmaf(av.y, w1.z, ac[2]);         \
  ac[2] = fmaf(av.z, w2.z, ac[2]); ac[2] = fmaf(av.w, w3.z, ac[2]);         \
  ac[3] = fmaf(av.x, w0.w, ac[3]); ac[3] = fmaf(av.y, w1.w, ac[3]);         \
  ac[3] = fmaf(av.z, w2.w, ac[3]); ac[3] = fmaf(av.w, w3.w, ac[3]);

// S=131072 samples. 2048 WGs x 512 threads (8 waves). Wave owns 8 samples
// end-to-end; weights resident in LDS; zero barriers in the 12-pass loop.
__global__ __launch_bounds__(512, 2)
void infl_kernel(const float* __restrict__ obs, const float* __restrict__ actions,
                 const float* __restrict__ W1, const float* __restrict__ b1,
                 const float* __restrict__ W2, const float* __restrict__ b2,
                 const float* __restrict__ W3, const float* __restrict__ b3,
                 float* __restrict__ out, TFKeys keys) {
  // 32K + 32K + 16K + 1K + 67K = 148.0 KB static LDS -> 1 WG/CU, 8 waves/CU
  __shared__ __align__(16) float s_w1a[64 * 128];   // pass weights; phase1: W1-obs stream buffer
  __shared__ __align__(16) float s_w2[128 * 64];
  __shared__ __align__(16) float s_w3[64 * 64];
  __shared__ float s_b1[128], s_b2[64], s_b3[64];
  __shared__ __align__(16) float s_scratch[8 * 2144]; // per wave: act 8x68 | h1 8x132 | h2 8x68 (phase1: obs 8x260)

  const int t    = threadIdx.x;
  const int wave = t >> 6;
  const int lane = t & 63;
  float* wsc   = &s_scratch[wave * 2144];
  float* s_act = wsc;                 // stride 68
  float* s_h1  = wsc + 544;           // stride 132
  float* s_h2  = wsc + 544 + 1056;    // stride 68
  const int g_base = blockIdx.x * 64 + wave * 8;   // first of this wave's 8 samples

  // ---- stage pass-invariant W2/W3/biases up front (used after phase-1 barrier)
  {
    const float4* src2 = (const float4*)W2;
    float4* dst2 = (float4*)s_w2;
#pragma unroll
    for (int i = 0; i < 4; ++i) dst2[t + i * 512] = src2[t + i * 512];
    const float4* src3 = (const float4*)W3;
    float4* dst3 = (float4*)s_w3;
#pragma unroll
    for (int i = 0; i < 2; ++i) dst3[t + i * 512] = src3[t + i * 512];
    if (t < 128)      s_b1[t] = b1[t];
    else if (t < 192) s_b2[t - 128] = b2[t - 128];
    else if (t < 256) s_b3[t - 192] = b3[t - 192];
  }

  // ---- stage this wave's obs (8 x 256 -> stride 260), intra-wave only
  {
    const float4* src = (const float4*)(obs + (size_t)g_base * 256);
#pragma unroll
    for (int i = 0; i < 8; ++i) {
      const int q = lane + (i << 6);            // float4 index 0..511
      const int s = q >> 6, c = (q & 63) << 2;
      *(float4*)(wsc + s * 260 + c) = src[q];
    }
  }

  // ---- phase 1: hobs = obs @ W1[0:256,:], streamed in 4 blocks of 64 rows
  const int s0 = (lane >> 5) << 2;   // sample group: 0 or 4
  const int c0 = (lane & 31) << 2;   // col group: 0..124
  float hobs[4][4];
#pragma unroll
  for (int r = 0; r < 4; ++r)
#pragma unroll
    for (int c = 0; c < 4; ++c) hobs[r][c] = 0.f;

  for (int blk = 0; blk < 4; ++blk) {
    __syncthreads();   // previous block's compute done
    {
      const float4* src = (const float4*)(W1 + (size_t)blk * 64 * 128);
      float4* dst = (float4*)s_w1a;
#pragma unroll
      for (int i = 0; i < 4; ++i) dst[t + i * 512] = src[t + i * 512];
    }
    __syncthreads();
    const int kb = blk << 6;
#pragma unroll 4
    for (int k = 0; k < 64; k += 4) {
      float4 w0 = *(const float4*)(s_w1a + (k + 0) * 128 + c0);
      float4 w1 = *(const float4*)(s_w1a + (k + 1) * 128 + c0);
      float4 w2 = *(const float4*)(s_w1a + (k + 2) * 128 + c0);
      float4 w3 = *(const float4*)(s_w1a + (k + 3) * 128 + c0);
#pragma unroll
      for (int r = 0; r < 4; ++r) {
        const float4 a = *(const float4*)(wsc + (s0 + r) * 260 + kb + k);
        FMA4(hobs[r], a, w0, w1, w2, w3)
      }
    }
  }

  // ---- stage W1 action part (rows 256..319); last barrier of the kernel
  __syncthreads();
  {
    const float4* src = (const float4*)(W1 + 256 * 128);
    float4* dst = (float4*)s_w1a;
#pragma unroll
    for (int i = 0; i < 4; ++i) dst[t + i * 512] = src[t + i * 512];
  }
  __syncthreads();

  // fold b1
#pragma unroll
  for (int c = 0; c < 4; ++c) {
    const float bv = s_b1[c0 + c];
#pragma unroll
    for (int r = 0; r < 4; ++r) hobs[r][c] += bv;
  }

  // L2/L3/epilogue lane map: 2 samples x 4 cols
  const int sg = lane >> 4;   // 0..3 -> samples 2sg,2sg+1
  const int c2 = (lane & 15) << 2;

  float pwith[2][4], pacc[2][4];
#pragma unroll
  for (int r = 0; r < 2; ++r)
#pragma unroll
    for (int c = 0; c < 4; ++c) pacc[r][c] = 0.f;

  // ---- 12 passes, barrier-free (per-wave scratch, in-order LDS per wave)
  for (int pass = 0; pass < 12; ++pass) {
    // act generation (pass 1 = zeros: skipped entirely)
    if (pass == 0) {
      const float4* src = (const float4*)(actions + (size_t)g_base * 64);
#pragma unroll
      for (int i = 0; i < 2; ++i) {
        const int q = lane + (i << 6);           // 0..127
        const int s = q >> 4, c = (q & 15) << 2;
        *(float4*)(s_act + s * 68 + c) = src[q];
      }
    } else if (pass >= 2) {
      const unsigned k0 = keys.k[2 * (pass - 2)];
      const unsigned k1 = keys.k[2 * (pass - 2) + 1];
      const int s = lane >> 3, cb = (lane & 7) << 3;
      const unsigned base = (unsigned)(g_base + s) * 64u + (unsigned)cb;
      float v[8];
#pragma unroll
      for (int e = 0; e < 8; ++e) {
        unsigned o0, o1;
        tf2x32(k0, k1, 0u, base + (unsigned)e, o0, o1);
        v[e] = u01(o0 ^ o1);
      }
      *(float4*)(s_act + s * 68 + cb)     = make_float4(v[0], v[1], v[2], v[3]);
      *(float4*)(s_act + s * 68 + cb + 4) = make_float4(v[4], v[5], v[6], v[7]);
    }

    // ---- layer 1: h1 = relu(hobs + act @ W1a)   (pass 1: act == 0)
    if (pass == 1) {
#pragma unroll
      for (int r = 0; r < 4; ++r) {
        float4 hv;
        hv.x = fmaxf(hobs[r][0], 0.f); hv.y = fmaxf(hobs[r][1], 0.f);
        hv.z = fmaxf(hobs[r][2], 0.f); hv.w = fmaxf(hobs[r][3], 0.f);
        *(float4*)(s_h1 + (s0 + r) * 132 + c0) = hv;
      }
    } else {
      float acc[4][4];
#pragma unroll
      for (int r = 0; r < 4; ++r)
#pragma unroll
        for (int c = 0; c < 4; ++c) acc[r][c] = 0.f;
#pragma unroll 4
      for (int k = 0; k < 64; k += 4) {
        float4 w0 = *(const float4*)(s_w1a + (k + 0) * 128 + c0);
        float4 w1 = *(const float4*)(s_w1a + (k + 1) * 128 + c0);
        float4 w2 = *(const float4*)(s_w1a + (k + 2) * 128 + c0);
        float4 w3 = *(const float4*)(s_w1a + (k + 3) * 128 + c0);
#pragma unroll
        for (int r = 0; r < 4; ++r) {
          const float4 a = *(const float4*)(s_act + (s0 + r) * 68 + k);
          FMA4(acc[r], a, w0, w1, w2, w3)
        }
      }
#pragma unroll
      for (int r = 0; r < 4; ++r) {
        float4 hv;
        hv.x = fmaxf(hobs[r][0] + acc[r][0], 0.f);
        hv.y = fmaxf(hobs[r][1] + acc[r][1], 0.f);
        hv.z = fmaxf(hobs[r][2] + acc[r][2], 0.f);
        hv.w = fmaxf(hobs[r][3] + acc[r][3], 0.f);
        *(float4*)(s_h1 + (s0 + r) * 132 + c0) = hv;
      }
    }

    // ---- layer 2: h2 = relu(h1 @ W2 + b2)
    float acc2[2][4];
#pragma unroll
    for (int r = 0; r < 2; ++r)
#pragma unroll
      for (int c = 0; c < 4; ++c) acc2[r][c] = 0.f;
#pragma unroll 4
    for (int k = 0; k < 128; k += 4) {
      float4 w0 = *(const float4*)(s_w2 + (k + 0) * 64 + c2);
      float4 w1 = *(const float4*)(s_w2 + (k + 1) * 64 + c2);
      float4 w2v = *(const float4*)(s_w2 + (k + 2) * 64 + c2);
      float4 w3 = *(const float4*)(s_w2 + (k + 3) * 64 + c2);
      const float4 a0 = *(const float4*)(s_h1 + (2 * sg + 0) * 132 + k);
      const float4 a1 = *(const float4*)(s_h1 + (2 * sg + 1) * 132 + k);
      FMA4(acc2[0], a0, w0, w1, w2v, w3)
      FMA4(acc2[1], a1, w0, w1, w2v, w3)
    }
#pragma unroll
    for (int r = 0; r < 2; ++r) {
      float4 hv;
      hv.x = fmaxf(acc2[r][0] + s_b2[c2 + 0], 0.f);
      hv.y = fmaxf(acc2[r][1] + s_b2[c2 + 1], 0.f);
      hv.z = fmaxf(acc2[r][2] + s_b2[c2 + 2], 0.f);
      hv.w = fmaxf(acc2[r][3] + s_b2[c2 + 3], 0.f);
      *(float4*)(s_h2 + (2 * sg + r) * 68 + c2) = hv;
    }

    // ---- layer 3: p = h2 @ W3 + b3
    float acc3[2][4];
#pragma unroll
    for (int r = 0; r < 2; ++r)
#pragma unroll
      for (int c = 0; c < 4; ++c) acc3[r][c] = 0.f;
#pragma unroll 4
    for (int k = 0; k < 64; k += 4) {
      float4 w0 = *(const float4*)(s_w3 + (k + 0) * 64 + c2);
      float4 w1 = *(const float4*)(s_w3 + (k + 1) * 64 + c2);
      float4 w2v = *(const float4*)(s_w3 + (k + 2) * 64 + c2);
      float4 w3 = *(const float4*)(s_w3 + (k + 3) * 64 + c2);
      const float4 a0 = *(const float4*)(s_h2 + (2 * sg + 0) * 68 + k);
      const float4 a1 = *(const float4*)(s_h2 + (2 * sg + 1) * 68 + k);
      FMA4(acc3[0], a0, w0, w1, w2v, w3)
      FMA4(acc3[1], a1, w0, w1, w2v, w3)
    }
    if (pass == 0) {
#pragma unroll
      for (int r = 0; r < 2; ++r)
#pragma unroll
        for (int c = 0; c < 4; ++c) pwith[r][c] = acc3[r][c] + s_b3[c2 + c];
    } else {
#pragma unroll
      for (int r = 0; r < 2; ++r)
#pragma unroll
        for (int c = 0; c < 4; ++c) pacc[r][c] += acc3[r][c] + s_b3[c2 + c];
    }
  }

  // ---- epilogue: influence = mean_a q*(logq-logp), 16-lane shfl reductions
  const float inv11 = 1.0f / 11.0f;
#pragma unroll
  for (int r = 0; r < 2; ++r) {
    float pw[4], pa[4];
#pragma unroll
    for (int c = 0; c < 4; ++c) { pw[c] = pwith[r][c]; pa[c] = pacc[r][c] * inv11; }
    float mw = fmaxf(fmaxf(pw[0], pw[1]), fmaxf(pw[2], pw[3]));
    float ma = fmaxf(fmaxf(pa[0], pa[1]), fmaxf(pa[2], pa[3]));
#pragma unroll
    for (int off = 1; off < 16; off <<= 1) {
      mw = fmaxf(mw, __shfl_xor(mw, off, 64));
      ma = fmaxf(ma, __shfl_xor(ma, off, 64));
    }
    float sw = 0.f, sa = 0.f;
#pragma unroll
    for (int c = 0; c < 4; ++c) { sw += expf(pw[c] - mw); sa += expf(pa[c] - ma); }
#pragma unroll
    for (int off = 1; off < 16; off <<= 1) {
      sw += __shfl_xor(sw, off, 64);
      sa += __shfl_xor(sa, off, 64);
    }
    const float lzw = logf(sw), lza = logf(sa);
    float contrib = 0.f;
#pragma unroll
    for (int c = 0; c < 4; ++c) {
      const float lq = pa[c] - ma - lza;
      const float lp = pw[c] - mw - lzw;
      contrib += expf(lq) * (lq - lp);
    }
#pragma unroll
    for (int off = 1; off < 16; off <<= 1)
      contrib += __shfl_xor(contrib, off, 64);
    if ((lane & 15) == 0) out[g_base + 2 * sg + r] = contrib * (1.0f / 64.0f);
  }
}

extern "C" void kernel_launch(void* const* d_in, const int* in_sizes, int n_in,
                              void* d_out, int out_size, void* d_ws, size_t ws_size,
                              hipStream_t stream) {
  (void)in_sizes; (void)n_in; (void)d_ws; (void)ws_size; (void)out_size;
  const float* obs     = (const float*)d_in[0];
  const float* actions = (const float*)d_in[1];
  const float* W1      = (const float*)d_in[2];
  const float* b1      = (const float*)d_in[3];
  const float* W2      = (const float*)d_in[4];
  const float* b2      = (const float*)d_in[5];
  const float* W3      = (const float*)d_in[6];
  const float* b3      = (const float*)d_in[7];

  TFKeys keys;
  for (unsigned j = 0; j < NCF; ++j) {
    unsigned o0, o1;
    tf2x32(0u, 42u, 0u, j, o0, o1);
    keys.k[2 * j]     = o0;
    keys.k[2 * j + 1] = o1;
  }

  hipLaunchKernelGGL(infl_kernel, dim3(2048), dim3(512), 0, stream,
                     obs, actions, W1, b1, W2, b2, W3, b3, (float*)d_out, keys);
}